// Round 7
// baseline (52.774 us; speedup 1.0000x reference)
//
#include <hip/hip_runtime.h>
#include <hip/hip_bf16.h>
#include <math.h>

#define NSEG 1024
#define DD 64
#define HH 32
#define XSTR 72   // LDS row stride in bf16 elems: 144 B rows -> 16B-aligned b128 reads

typedef __attribute__((ext_vector_type(8))) short bf16x8;
typedef __attribute__((ext_vector_type(4))) float f32x4;

// Kernel 1: segment offsets by boundary scatter (batch sorted int32).
__global__ void seg_off_scatter(const int* __restrict__ batch, int n,
                                int* __restrict__ off) {
    int i = blockIdx.x * blockDim.x + threadIdx.x;
    if (i >= n) return;
    int b1 = batch[i];
    int b0 = (i == 0) ? -1 : batch[i - 1];
    for (int t = b0 + 1; t <= b1; ++t) off[t] = i;      // usually 0 or 1 iters
    if (i == n - 1)
        for (int t = b1 + 1; t <= NSEG; ++t) off[t] = n;
}

__device__ __forceinline__ unsigned short f2bf_u(float f) {
    return __builtin_bit_cast(unsigned short, __float2bfloat16(f));
}
__device__ __forceinline__ short f2bf(float f) { return (short)f2bf_u(f); }
__device__ __forceinline__ float bf2f(unsigned short s) {
    return __builtin_bit_cast(float, ((unsigned)s) << 16);
}

// Single-pass kernel. One block per segment; 64-node tiles block-cooperative:
// wave w owns nodes [16w,16w+16) (gate MFMA) and dim-rows [16w,16w+16) of U^T
// (pooled MFMA). Per tile: gates = x@Wg -> e = bf16(exp(g+b)); x^T,e^T staged
// to double-buffered LDS; U^T += X^T@E.
// The in-loop barrier is RAW s_barrier with lgkmcnt(0) only (no vmcnt drain):
// next-tile global prefetch stays in flight across the barrier. The compiler's
// own vmcnt wait before the next iteration's pack covers the data dependency.
__launch_bounds__(256, 4)
__global__ void gattp_kernel(const float* __restrict__ x,
                             const float* __restrict__ Wg,
                             const float* __restrict__ bg,
                             const int* __restrict__ off,
                             float* __restrict__ out) {
    const int seg = blockIdx.x;
    const int tid = threadIdx.x;
    const int w = tid >> 6;     // wave
    const int l = tid & 63;     // lane
    const int r = l & 15;       // A-row / B-col / C-col index
    const int a = l >> 4;       // k-subgroup / C-row-group

    __shared__ short xt[2][DD * XSTR];   // X^T tile: [dim][node], bf16
    __shared__ short et[2][HH * XSTR];   // E^T tile: [head][node], bf16
    __shared__ float sden[4][HH];

    const int start = off[seg];
    const int end   = off[seg + 1];
    if (start >= end) {                  // empty segment -> relu(0)=0
        if (tid < DD) out[seg * DD + tid] = 0.0f;
        return;
    }

    // Wg B-frags, persistent: bfrag[kt][nt][j] = Wg[32kt+8a+j][16nt+r]
    bf16x8 bfrag[2][2];
#pragma unroll
    for (int kt = 0; kt < 2; ++kt)
#pragma unroll
        for (int nt = 0; nt < 2; ++nt) {
            bf16x8 f;
#pragma unroll
            for (int j = 0; j < 8; ++j)
                f[j] = f2bf(Wg[(32 * kt + 8 * a + j) * HH + 16 * nt + r]);
            bfrag[kt][nt] = f;
        }
    const float bg0 = bg[r];
    const float bg1 = bg[16 + r];

    const int ntile = (end - start + 63) >> 6;

    f32x4 uacc0 = {0.f, 0.f, 0.f, 0.f};   // U^T[16w+4a+rr][r]      (heads 0-15)
    f32x4 uacc1 = {0.f, 0.f, 0.f, 0.f};   // U^T[16w+4a+rr][16+r]   (heads 16-31)
    float s0 = 0.f, s1 = 0.f;             // per-head denominator partials

    // load tile 0: this wave's 16 node-rows, lane r -> node, dims 8a+j (+32)
    float4 c0, c1, c2, c3;
    {
        int node = start + 16 * w + r;
        if (node >= end) node = end - 1;
        const float* rp = x + (size_t)node * DD + 8 * a;
        c0 = *reinterpret_cast<const float4*>(rp);
        c1 = *reinterpret_cast<const float4*>(rp + 4);
        c2 = *reinterpret_cast<const float4*>(rp + 32);
        c3 = *reinterpret_cast<const float4*>(rp + 36);
    }

    for (int t = 0; t < ntile; ++t) {
        // ---- prefetch next tile (issued before any dependent use of c*) ----
        const int tn = (t + 1 < ntile) ? t + 1 : t;
        int node_n = start + (tn << 6) + 16 * w + r;
        if (node_n >= end) node_n = end - 1;
        const float* rpn = x + (size_t)node_n * DD + 8 * a;
        float4 n0 = *reinterpret_cast<const float4*>(rpn);
        float4 n1 = *reinterpret_cast<const float4*>(rpn + 4);
        float4 n2 = *reinterpret_cast<const float4*>(rpn + 32);
        float4 n3 = *reinterpret_cast<const float4*>(rpn + 36);

        const int buf = t & 1;
        // ---- pack current x rows to bf16 A-frags ----
        bf16x8 af0, af1;
        af0[0] = f2bf(c0.x); af0[1] = f2bf(c0.y); af0[2] = f2bf(c0.z); af0[3] = f2bf(c0.w);
        af0[4] = f2bf(c1.x); af0[5] = f2bf(c1.y); af0[6] = f2bf(c1.z); af0[7] = f2bf(c1.w);
        af1[0] = f2bf(c2.x); af1[1] = f2bf(c2.y); af1[2] = f2bf(c2.z); af1[3] = f2bf(c2.w);
        af1[4] = f2bf(c3.x); af1[5] = f2bf(c3.y); af1[6] = f2bf(c3.z); af1[7] = f2bf(c3.w);

        // ---- stage X^T: xt[dim 8a+j (+32)][node-in-tile 16w+r] ----
        short* xb = xt[buf];
        const int colw = 16 * w + r;
#pragma unroll
        for (int j = 0; j < 8; ++j) {
            xb[(8 * a + j) * XSTR + colw]        = af0[j];
            xb[(32 + 8 * a + j) * XSTR + colw]   = af1[j];
        }

        // ---- gate MFMA: gates[16w+4a+rr][16nt+r] ----
        f32x4 g0 = {0.f, 0.f, 0.f, 0.f}, g1 = {0.f, 0.f, 0.f, 0.f};
        g0 = __builtin_amdgcn_mfma_f32_16x16x32_bf16(af0, bfrag[0][0], g0, 0, 0, 0);
        g0 = __builtin_amdgcn_mfma_f32_16x16x32_bf16(af1, bfrag[1][0], g0, 0, 0, 0);
        g1 = __builtin_amdgcn_mfma_f32_16x16x32_bf16(af0, bfrag[0][1], g1, 0, 0, 0);
        g1 = __builtin_amdgcn_mfma_f32_16x16x32_bf16(af1, bfrag[1][1], g1, 0, 0, 0);

        // ---- e = bf16(exp(g + b)), masked; denominators from ROUNDED e ----
        const int nodeb = start + (t << 6) + 16 * w + 4 * a;
        unsigned short u0[4], u1[4];
#pragma unroll
        for (int rr = 0; rr < 4; ++rr) {
            const bool v = (nodeb + rr) < end;
            unsigned short b0 = v ? f2bf_u(__expf(g0[rr] + bg0)) : (unsigned short)0;
            unsigned short b1 = v ? f2bf_u(__expf(g1[rr] + bg1)) : (unsigned short)0;
            s0 += bf2f(b0);
            s1 += bf2f(b1);
            u0[rr] = b0; u1[rr] = b1;
        }
        // stage E^T: et[head][node-in-tile], packed u32 pairs
        short* eb = et[buf];
        const int colb = 16 * w + 4 * a;
        *reinterpret_cast<unsigned*>(&eb[r * XSTR + colb])            = ((unsigned)u0[1] << 16) | u0[0];
        *reinterpret_cast<unsigned*>(&eb[r * XSTR + colb + 2])        = ((unsigned)u0[3] << 16) | u0[2];
        *reinterpret_cast<unsigned*>(&eb[(16 + r) * XSTR + colb])     = ((unsigned)u1[1] << 16) | u1[0];
        *reinterpret_cast<unsigned*>(&eb[(16 + r) * XSTR + colb + 2]) = ((unsigned)u1[3] << 16) | u1[2];

        // ---- raw barrier: drain LDS only; global prefetch stays in flight ----
        asm volatile("s_waitcnt lgkmcnt(0)" ::: "memory");
        __builtin_amdgcn_s_barrier();
        __builtin_amdgcn_sched_barrier(0);   // no compiler motion across barrier

        // ---- U^T += X^T @ E : A-rows = dims 16w+r, B-cols = heads 16nt+r ----
        const short* xr_ = xt[buf];
        const short* er_ = et[buf];
        bf16x8 xf0  = *reinterpret_cast<const bf16x8*>(&xr_[(16 * w + r) * XSTR + 8 * a]);
        bf16x8 xf1  = *reinterpret_cast<const bf16x8*>(&xr_[(16 * w + r) * XSTR + 32 + 8 * a]);
        bf16x8 ef00 = *reinterpret_cast<const bf16x8*>(&er_[r * XSTR + 8 * a]);
        bf16x8 ef10 = *reinterpret_cast<const bf16x8*>(&er_[r * XSTR + 32 + 8 * a]);
        bf16x8 ef01 = *reinterpret_cast<const bf16x8*>(&er_[(16 + r) * XSTR + 8 * a]);
        bf16x8 ef11 = *reinterpret_cast<const bf16x8*>(&er_[(16 + r) * XSTR + 32 + 8 * a]);
        uacc0 = __builtin_amdgcn_mfma_f32_16x16x32_bf16(xf0, ef00, uacc0, 0, 0, 0);
        uacc0 = __builtin_amdgcn_mfma_f32_16x16x32_bf16(xf1, ef10, uacc0, 0, 0, 0);
        uacc1 = __builtin_amdgcn_mfma_f32_16x16x32_bf16(xf0, ef01, uacc1, 0, 0, 0);
        uacc1 = __builtin_amdgcn_mfma_f32_16x16x32_bf16(xf1, ef11, uacc1, 0, 0, 0);

        c0 = n0; c1 = n1; c2 = n2; c3 = n3;
    }

    // ---- denominators: reduce over C-row-groups (a), then over waves ----
    s0 += __shfl_xor(s0, 16, 64); s0 += __shfl_xor(s0, 32, 64);
    s1 += __shfl_xor(s1, 16, 64); s1 += __shfl_xor(s1, 32, 64);
    if (l < 16) { sden[w][l] = s0; sden[w][16 + l] = s1; }
    __syncthreads();
    const float st0 = sden[0][r] + sden[1][r] + sden[2][r] + sden[3][r];
    const float st1 = sden[0][16 + r] + sden[1][16 + r] + sden[2][16 + r] + sden[3][16 + r];
    const float wi0 = 1.0f / (32.0f * st0);
    const float wi1 = 1.0f / (32.0f * st1);

    // pooled[16w+4a+rr] = sum_h U^T[d][h] * winv[h]; butterfly over 16 h-lanes
    float tt[4];
#pragma unroll
    for (int rr = 0; rr < 4; ++rr) {
        float v = uacc0[rr] * wi0 + uacc1[rr] * wi1;
        v += __shfl_xor(v, 1, 64);
        v += __shfl_xor(v, 2, 64);
        v += __shfl_xor(v, 4, 64);
        v += __shfl_xor(v, 8, 64);
        tt[rr] = v;
    }
    if (r == 0) {
        float4 o;
        o.x = fmaxf(tt[0], 0.0f);
        o.y = fmaxf(tt[1], 0.0f);
        o.z = fmaxf(tt[2], 0.0f);
        o.w = fmaxf(tt[3], 0.0f);
        *reinterpret_cast<float4*>(&out[seg * DD + 16 * w + 4 * a]) = o;
    }
}

extern "C" void kernel_launch(void* const* d_in, const int* in_sizes, int n_in,
                              void* d_out, int out_size, void* d_ws, size_t ws_size,
                              hipStream_t stream) {
    const float* x     = (const float*)d_in[0];
    const int*   batch = (const int*)d_in[1];
    const float* Wg    = (const float*)d_in[2];
    const float* bg    = (const float*)d_in[3];
    float* out = (float*)d_out;
    const int N = in_sizes[1];          // 1,000,000 nodes
    int* off = (int*)d_ws;              // NSEG+1 ints

    seg_off_scatter<<<(N + 255) / 256, 256, 0, stream>>>(batch, N, off);
    gattp_kernel<<<NSEG, 256, 0, stream>>>(x, Wg, bg, off, out);
}

// Round 8
// 49.620 us; speedup vs baseline: 1.0636x; 1.0636x over previous
//
#include <hip/hip_runtime.h>
#include <hip/hip_bf16.h>
#include <math.h>

#define NSEG 1024
#define DD 64
#define HH 32
#define XSTR 72   // LDS row stride in bf16 elems: 144 B rows -> 16B-aligned b128 reads

typedef __attribute__((ext_vector_type(8))) short bf16x8;
typedef __attribute__((ext_vector_type(4))) float f32x4;

__device__ __forceinline__ unsigned short f2bf_u(float f) {
    return __builtin_bit_cast(unsigned short, __float2bfloat16(f));
}
__device__ __forceinline__ short f2bf(float f) { return (short)f2bf_u(f); }
__device__ __forceinline__ float bf2f(unsigned short s) {
    return __builtin_bit_cast(float, ((unsigned)s) << 16);
}

// Cooperative wave-wide lower_bound: first i with batch[i] >= v.
// Invariant: answer in [lo, lo+len]. 64 probes/round: 1e6 -> 15625 -> 245 -> 4 -> 1
// (~4 dependent load rounds instead of ~20 for a scalar binary search).
__device__ __forceinline__ int coop_lower_bound(const int* __restrict__ batch,
                                                int n, int v, int lane) {
    int lo = 0, len = n;
    while (len > 0) {
        int step = (len + 63) >> 6;                  // ceil(len/64)
        bool lt = false;
        if (lane * step < len) lt = batch[lo + lane * step] < v;
        unsigned long long m = __ballot(lt);         // prefix mask (sorted input)
        int cnt = __popcll(m);
        if (cnt == 0) break;                         // batch[lo] >= v -> answer = lo
        int newlo = lo + (cnt - 1) * step + 1;
        int hi    = (cnt * step < len) ? cnt * step : len;   // answer <= lo+hi
        len = hi - ((cnt - 1) * step + 1);
        lo = newlo;
    }
    return lo;
}

// Single fused kernel. One block per segment; block finds its own node range
// via cooperative search (no precompute kernel, no workspace). 64-node tiles
// block-cooperative: wave w owns nodes [16w,16w+16) (gate MFMA) and dim-rows
// [16w,16w+16) of U^T (pooled MFMA). Per tile: gates = x@Wg -> e =
// bf16(exp(g+b)); x^T,e^T staged to double-buffered LDS; U^T += X^T@E.
// In-loop barrier is raw s_barrier + lgkmcnt(0) only: next-tile global
// prefetch stays in flight across it (compiler's own counted vmcnt covers the
// data dep at the next iteration's pack).
__launch_bounds__(256, 4)
__global__ void gattp_kernel(const float* __restrict__ x,
                             const int* __restrict__ batch,
                             const float* __restrict__ Wg,
                             const float* __restrict__ bg,
                             float* __restrict__ out, int N) {
    const int seg = blockIdx.x;
    const int tid = threadIdx.x;
    const int w = tid >> 6;     // wave
    const int l = tid & 63;     // lane
    const int r = l & 15;       // A-row / B-col / C-col index
    const int a = l >> 4;       // k-subgroup / C-row-group

    __shared__ short xt[2][DD * XSTR];   // X^T tile: [dim][node], bf16
    __shared__ short et[2][HH * XSTR];   // E^T tile: [head][node], bf16
    __shared__ float sden[4][HH];
    __shared__ int bounds[2];

    // ---- Wg B-frags first (independent of bounds; latency hides under search)
    bf16x8 bfrag[2][2];
#pragma unroll
    for (int kt = 0; kt < 2; ++kt)
#pragma unroll
        for (int nt = 0; nt < 2; ++nt) {
            bf16x8 f;
#pragma unroll
            for (int j = 0; j < 8; ++j)
                f[j] = f2bf(Wg[(32 * kt + 8 * a + j) * HH + 16 * nt + r]);
            bfrag[kt][nt] = f;
        }
    const float bg0 = bg[r];
    const float bg1 = bg[16 + r];

    // ---- cooperative segment bounds: wave 0 -> start, wave 1 -> end ----
    if (w < 2) {
        int b = coop_lower_bound(batch, N, seg + w, l);
        if (l == 0) bounds[w] = b;
    }
    __syncthreads();
    const int start = bounds[0];
    const int end   = bounds[1];
    if (start >= end) {                  // empty segment -> relu(0)=0
        if (tid < DD) out[seg * DD + tid] = 0.0f;
        return;
    }

    const int ntile = (end - start + 63) >> 6;

    f32x4 uacc0 = {0.f, 0.f, 0.f, 0.f};   // U^T[16w+4a+rr][r]      (heads 0-15)
    f32x4 uacc1 = {0.f, 0.f, 0.f, 0.f};   // U^T[16w+4a+rr][16+r]   (heads 16-31)
    float s0 = 0.f, s1 = 0.f;             // per-head denominator partials

    // load tile 0: this wave's 16 node-rows, lane r -> node, dims 8a+j (+32)
    float4 c0, c1, c2, c3;
    {
        int node = start + 16 * w + r;
        if (node >= end) node = end - 1;
        const float* rp = x + (size_t)node * DD + 8 * a;
        c0 = *reinterpret_cast<const float4*>(rp);
        c1 = *reinterpret_cast<const float4*>(rp + 4);
        c2 = *reinterpret_cast<const float4*>(rp + 32);
        c3 = *reinterpret_cast<const float4*>(rp + 36);
    }

    for (int t = 0; t < ntile; ++t) {
        // ---- prefetch next tile (issued before any dependent use of c*) ----
        const int tn = (t + 1 < ntile) ? t + 1 : t;
        int node_n = start + (tn << 6) + 16 * w + r;
        if (node_n >= end) node_n = end - 1;
        const float* rpn = x + (size_t)node_n * DD + 8 * a;
        float4 n0 = *reinterpret_cast<const float4*>(rpn);
        float4 n1 = *reinterpret_cast<const float4*>(rpn + 4);
        float4 n2 = *reinterpret_cast<const float4*>(rpn + 32);
        float4 n3 = *reinterpret_cast<const float4*>(rpn + 36);

        const int buf = t & 1;
        // ---- pack current x rows to bf16 A-frags ----
        bf16x8 af0, af1;
        af0[0] = f2bf(c0.x); af0[1] = f2bf(c0.y); af0[2] = f2bf(c0.z); af0[3] = f2bf(c0.w);
        af0[4] = f2bf(c1.x); af0[5] = f2bf(c1.y); af0[6] = f2bf(c1.z); af0[7] = f2bf(c1.w);
        af1[0] = f2bf(c2.x); af1[1] = f2bf(c2.y); af1[2] = f2bf(c2.z); af1[3] = f2bf(c2.w);
        af1[4] = f2bf(c3.x); af1[5] = f2bf(c3.y); af1[6] = f2bf(c3.z); af1[7] = f2bf(c3.w);

        // ---- stage X^T: xt[dim 8a+j (+32)][node-in-tile 16w+r] ----
        short* xb = xt[buf];
        const int colw = 16 * w + r;
#pragma unroll
        for (int j = 0; j < 8; ++j) {
            xb[(8 * a + j) * XSTR + colw]        = af0[j];
            xb[(32 + 8 * a + j) * XSTR + colw]   = af1[j];
        }

        // ---- gate MFMA: gates[16w+4a+rr][16nt+r] ----
        f32x4 g0 = {0.f, 0.f, 0.f, 0.f}, g1 = {0.f, 0.f, 0.f, 0.f};
        g0 = __builtin_amdgcn_mfma_f32_16x16x32_bf16(af0, bfrag[0][0], g0, 0, 0, 0);
        g0 = __builtin_amdgcn_mfma_f32_16x16x32_bf16(af1, bfrag[1][0], g0, 0, 0, 0);
        g1 = __builtin_amdgcn_mfma_f32_16x16x32_bf16(af0, bfrag[0][1], g1, 0, 0, 0);
        g1 = __builtin_amdgcn_mfma_f32_16x16x32_bf16(af1, bfrag[1][1], g1, 0, 0, 0);

        // ---- e = bf16(exp(g + b)), masked; denominators from ROUNDED e ----
        const int nodeb = start + (t << 6) + 16 * w + 4 * a;
        unsigned short u0[4], u1[4];
#pragma unroll
        for (int rr = 0; rr < 4; ++rr) {
            const bool v = (nodeb + rr) < end;
            unsigned short b0 = v ? f2bf_u(__expf(g0[rr] + bg0)) : (unsigned short)0;
            unsigned short b1 = v ? f2bf_u(__expf(g1[rr] + bg1)) : (unsigned short)0;
            s0 += bf2f(b0);
            s1 += bf2f(b1);
            u0[rr] = b0; u1[rr] = b1;
        }
        // stage E^T: et[head][node-in-tile], packed u32 pairs
        short* eb = et[buf];
        const int colb = 16 * w + 4 * a;
        *reinterpret_cast<unsigned*>(&eb[r * XSTR + colb])            = ((unsigned)u0[1] << 16) | u0[0];
        *reinterpret_cast<unsigned*>(&eb[r * XSTR + colb + 2])        = ((unsigned)u0[3] << 16) | u0[2];
        *reinterpret_cast<unsigned*>(&eb[(16 + r) * XSTR + colb])     = ((unsigned)u1[1] << 16) | u1[0];
        *reinterpret_cast<unsigned*>(&eb[(16 + r) * XSTR + colb + 2]) = ((unsigned)u1[3] << 16) | u1[2];

        // ---- raw barrier: drain LDS only; global prefetch stays in flight ----
        asm volatile("s_waitcnt lgkmcnt(0)" ::: "memory");
        __builtin_amdgcn_s_barrier();
        __builtin_amdgcn_sched_barrier(0);   // no compiler motion across barrier

        // ---- U^T += X^T @ E : A-rows = dims 16w+r, B-cols = heads 16nt+r ----
        const short* xr_ = xt[buf];
        const short* er_ = et[buf];
        bf16x8 xf0  = *reinterpret_cast<const bf16x8*>(&xr_[(16 * w + r) * XSTR + 8 * a]);
        bf16x8 xf1  = *reinterpret_cast<const bf16x8*>(&xr_[(16 * w + r) * XSTR + 32 + 8 * a]);
        bf16x8 ef00 = *reinterpret_cast<const bf16x8*>(&er_[r * XSTR + 8 * a]);
        bf16x8 ef10 = *reinterpret_cast<const bf16x8*>(&er_[r * XSTR + 32 + 8 * a]);
        bf16x8 ef01 = *reinterpret_cast<const bf16x8*>(&er_[(16 + r) * XSTR + 8 * a]);
        bf16x8 ef11 = *reinterpret_cast<const bf16x8*>(&er_[(16 + r) * XSTR + 32 + 8 * a]);
        uacc0 = __builtin_amdgcn_mfma_f32_16x16x32_bf16(xf0, ef00, uacc0, 0, 0, 0);
        uacc0 = __builtin_amdgcn_mfma_f32_16x16x32_bf16(xf1, ef10, uacc0, 0, 0, 0);
        uacc1 = __builtin_amdgcn_mfma_f32_16x16x32_bf16(xf0, ef01, uacc1, 0, 0, 0);
        uacc1 = __builtin_amdgcn_mfma_f32_16x16x32_bf16(xf1, ef11, uacc1, 0, 0, 0);

        c0 = n0; c1 = n1; c2 = n2; c3 = n3;
    }

    // ---- denominators: reduce over C-row-groups (a), then over waves ----
    s0 += __shfl_xor(s0, 16, 64); s0 += __shfl_xor(s0, 32, 64);
    s1 += __shfl_xor(s1, 16, 64); s1 += __shfl_xor(s1, 32, 64);
    if (l < 16) { sden[w][l] = s0; sden[w][16 + l] = s1; }
    __syncthreads();
    const float st0 = sden[0][r] + sden[1][r] + sden[2][r] + sden[3][r];
    const float st1 = sden[0][16 + r] + sden[1][16 + r] + sden[2][16 + r] + sden[3][16 + r];
    const float wi0 = 1.0f / (32.0f * st0);
    const float wi1 = 1.0f / (32.0f * st1);

    // pooled[16w+4a+rr] = sum_h U^T[d][h] * winv[h]; butterfly over 16 h-lanes
    float tt[4];
#pragma unroll
    for (int rr = 0; rr < 4; ++rr) {
        float v = uacc0[rr] * wi0 + uacc1[rr] * wi1;
        v += __shfl_xor(v, 1, 64);
        v += __shfl_xor(v, 2, 64);
        v += __shfl_xor(v, 4, 64);
        v += __shfl_xor(v, 8, 64);
        tt[rr] = v;
    }
    if (r == 0) {
        float4 o;
        o.x = fmaxf(tt[0], 0.0f);
        o.y = fmaxf(tt[1], 0.0f);
        o.z = fmaxf(tt[2], 0.0f);
        o.w = fmaxf(tt[3], 0.0f);
        *reinterpret_cast<float4*>(&out[seg * DD + 16 * w + 4 * a]) = o;
    }
}

extern "C" void kernel_launch(void* const* d_in, const int* in_sizes, int n_in,
                              void* d_out, int out_size, void* d_ws, size_t ws_size,
                              hipStream_t stream) {
    const float* x     = (const float*)d_in[0];
    const int*   batch = (const int*)d_in[1];
    const float* Wg    = (const float*)d_in[2];
    const float* bg    = (const float*)d_in[3];
    float* out = (float*)d_out;
    const int N = in_sizes[1];          // 1,000,000 nodes

    gattp_kernel<<<NSEG, 256, 0, stream>>>(x, batch, Wg, bg, out, N);
}